// Round 1
// baseline (769.802 us; speedup 1.0000x reference)
//
#include <hip/hip_runtime.h>

#define E_EDGES 250000
#define D_IN    64
#define C_OUT   64
#define EPG     8      // edges per wave-group
#define BLOCK   256
#define GRID    1024

__global__ __launch_bounds__(BLOCK, 3)
void TwoBodySphericalHarmonicTensorEmbed_kernel(
    const float* __restrict__ edge_vec,     // [E,3]
    const float* __restrict__ inv,          // [E,64]
    const float* __restrict__ W,            // [64, 192] (col = c*3 + irrep)
    float* __restrict__ out)                // [E, 64, 9]
{
    // [irrep][k][c] : lane=c reads bank lane%32 -> conflict-free (2-way alias is free)
    __shared__ float Ws[3][D_IN][C_OUT];    // 48 KB

    for (int idx = threadIdx.x; idx < D_IN * C_OUT * 3; idx += BLOCK) {
        float v = W[idx];                   // coalesced read of W_lin
        int k = idx / 192;
        int r = idx - k * 192;
        int c = r / 3;
        int i = r - c * 3;
        Ws[i][k][c] = v;
    }
    __syncthreads();

    const int lane  = threadIdx.x & 63;     // = output channel c
    const int wib   = threadIdx.x >> 6;
    const int wgid  = blockIdx.x * (BLOCK / 64) + wib;
    const int nw    = GRID * (BLOCK / 64);
    const int ngroups = E_EDGES / EPG;      // 31250 exactly

    const float SQ3  = 1.7320508075688772f;
    const float SQ5  = 2.2360679774997896f;
    const float SQ15 = 3.8729833462074170f;

    for (int g0 = wgid; g0 < ngroups; g0 += nw) {
        const int g     = __builtin_amdgcn_readfirstlane(g0);  // wave-uniform -> s_load path
        const int ebase = g * EPG;

        float acc[EPG][3];
        #pragma unroll
        for (int j = 0; j < EPG; ++j) {
            acc[j][0] = 0.f; acc[j][1] = 0.f; acc[j][2] = 0.f;
        }

        const float* __restrict__ ip = inv + (size_t)ebase * D_IN;

        #pragma unroll 4
        for (int k = 0; k < D_IN; ++k) {
            float w0 = Ws[0][k][lane];
            float w1 = Ws[1][k][lane];
            float w2 = Ws[2][k][lane];
            #pragma unroll
            for (int j = 0; j < EPG; ++j) {
                float s = ip[j * D_IN + k];            // wave-uniform scalar load
                acc[j][0] = fmaf(w0, s, acc[j][0]);
                acc[j][1] = fmaf(w1, s, acc[j][1]);
                acc[j][2] = fmaf(w2, s, acc[j][2]);
            }
        }

        #pragma unroll
        for (int j = 0; j < EPG; ++j) {
            const int e = ebase + j;
            float x = edge_vec[e * 3 + 0];
            float y = edge_vec[e * 3 + 1];
            float z = edge_vec[e * 3 + 2];
            float rn = rsqrtf(fmaf(x, x, fmaf(y, y, z * z)));
            x *= rn; y *= rn; z *= rn;

            float sh1 = SQ3 * x;
            float sh2 = SQ3 * y;
            float sh3 = SQ3 * z;
            float sh4 = SQ15 * x * z;
            float sh5 = SQ15 * x * y;
            float sh6 = SQ5 * (y * y - 0.5f * (x * x + z * z));
            float sh7 = SQ15 * y * z;
            float sh8 = SQ5 * (SQ3 * 0.5f) * (z * z - x * x);

            const float a0 = acc[j][0], a1 = acc[j][1], a2 = acc[j][2];
            float* __restrict__ op = out + ((size_t)e * C_OUT + lane) * 9;
            op[0] = a0;            // sh0 = 1
            op[1] = sh1 * a1;
            op[2] = sh2 * a1;
            op[3] = sh3 * a1;
            op[4] = sh4 * a2;
            op[5] = sh5 * a2;
            op[6] = sh6 * a2;
            op[7] = sh7 * a2;
            op[8] = sh8 * a2;
        }
    }
}

extern "C" void kernel_launch(void* const* d_in, const int* in_sizes, int n_in,
                              void* d_out, int out_size, void* d_ws, size_t ws_size,
                              hipStream_t stream) {
    const float* edge_vec = (const float*)d_in[0];
    const float* inv      = (const float*)d_in[1];
    const float* W        = (const float*)d_in[2];
    float* out            = (float*)d_out;

    TwoBodySphericalHarmonicTensorEmbed_kernel<<<dim3(GRID), dim3(BLOCK), 0, stream>>>(
        edge_vec, inv, W, out);
}